// Round 4
// baseline (282.456 us; speedup 1.0000x reference)
//
#include <hip/hip_runtime.h>
#include <math.h>

// ---------------------------------------------------------------------------
// cross_scale_attention v8: v7 + GEMM1 rescheduled (512 thr / 8 waves,
// BK=64, 2-deep LDS dbuf 64KB -> 2 blocks/CU, counted vmcnt(4), phase-split
// compute with setprio). Everything else identical to v7.
//   qps[n][f][385][97][64] f16 <- conv3(pan, wq, bq); entry (f,y',xi) = pixel
//        (y', 4*xi+f), zero if y'>=384 or 4*xi+f>=384  (SAME-pad)
//   kcl[n][96][96][64]   f16 <- conv3(pan2, wk, bk), channels-last
//   v_fea fp32           <- conv3(ms, wv, bv)
//   Kmat[n][l][(kh,kw,c)] f16 (640 rows, pad 0) + norms  <- kcl gather
//   Vt[n][m][l] f16 (256x576)
//   scoresT[n][p][l576] = implicit-Q x Kmat^T   (MFMA GEMM1, A from qps)
//   attnT[n][p][l] f16  = softmax * 10/maxnorm
//   D[n][m][p] = Vt x attnT^T                   (MFMA GEMM2, 64x128 tile)
//   out = conv3_8x8(gather(D)/6)  (fused, res tile staged in LDS)
// ---------------------------------------------------------------------------

typedef _Float16 f16;
typedef _Float16 f16x8 __attribute__((ext_vector_type(8)));
typedef float f32x4 __attribute__((ext_vector_type(4)));

namespace csa {
constexpr int NB   = 2;
constexpr int MID  = 64;
constexpr int BAND = 8;
constexpr int HK   = 96;
constexpr int HQ   = 384;
constexpr int HQP  = 385;
constexpr int XI   = 97;            // xi range per phase
constexpr int LN   = 24;
constexpr int L    = 576;
constexpr int LP   = 640;
constexpr int PS   = 96 * 96;       // 9216
constexpr int KDIM = MID * 25;      // 1600
constexpr int VDIM = BAND * 25;     // 200
constexpr int MV   = 256;
constexpr int HO   = 385;
constexpr size_t QPSN = (size_t)4 * HQP * XI * MID;  // per-batch qps elems

constexpr int NBQ = (NB * 4 * HQP * XI + 255) / 256;  // 1168 conv-q blocks
constexpr int NBC = NB * HK * HK / 256;               // 72 blocks each

constexpr size_t align256(size_t x) { return (x + 255) & ~(size_t)255; }
constexpr size_t OFF_QPS  = 0;                                            // f16 NB*QPSN
constexpr size_t OFF_KCL  = align256(OFF_QPS + (size_t)NB*QPSN*2);        // f16 NB*96*96*64
constexpr size_t OFF_VFEA = align256(OFF_KCL + (size_t)NB*HK*HK*MID*2);   // f32 NB*8*96*96
constexpr size_t OFF_N2   = align256(OFF_VFEA + (size_t)NB*BAND*HK*HK*4);
constexpr size_t OFF_SC   = align256(OFF_N2   + (size_t)NB*L*4);
constexpr size_t OFF_KM   = align256(OFF_SC   + 256);                     // f16 NB*640*1600
constexpr size_t OFF_VT   = align256(OFF_KM   + (size_t)NB*LP*KDIM*2);    // f16 NB*256*576
constexpr size_t OFF_ST   = align256(OFF_VT   + (size_t)NB*MV*L*2);      // f32 NB*9216*576
constexpr size_t OFF_AT   = align256(OFF_ST   + (size_t)NB*PS*LP*4);      // f16 NB*9216*576
constexpr size_t OFF_D    = align256(OFF_AT   + (size_t)NB*PS*L*2);       // f32 NB*256*9216
}  // namespace csa
using namespace csa;

// ----------------------------- conv device bodies ---------------------------
__device__ __forceinline__ void dev_convq(
    const float* __restrict__ in, const float* __restrict__ w,
    const float* __restrict__ b, f16* __restrict__ out, int id) {
  int total = NB * 4 * HQP * XI;
  if (id >= total) return;
  int xi = id % XI;
  int t = id / XI;
  int yp = t % HQP;
  t /= HQP;
  int f = t % 4;
  int n = t / 4;
  int xp = 4 * xi + f;
  f16* op = out + (size_t)id * MID;
  if (yp >= HQ || xp >= HQ) {
    f16x8 z = {0, 0, 0, 0, 0, 0, 0, 0};
#pragma unroll
    for (int c8 = 0; c8 < 8; ++c8) *(f16x8*)(op + c8 * 8) = z;
    return;
  }
  const float* ip = in + (size_t)n * HQ * HQ;
  float p[9];
#pragma unroll
  for (int dy = 0; dy < 3; ++dy)
#pragma unroll
    for (int dx = 0; dx < 3; ++dx) {
      int yy = yp + dy - 1, xx = xp + dx - 1;
      p[dy * 3 + dx] = (yy >= 0 && yy < HQ && xx >= 0 && xx < HQ)
                           ? ip[(size_t)yy * HQ + xx] : 0.f;
    }
#pragma unroll
  for (int c8 = 0; c8 < 8; ++c8) {
    f16x8 o;
#pragma unroll
    for (int e = 0; e < 8; ++e) {
      int co = c8 * 8 + e;
      float acc = b[co];
#pragma unroll
      for (int k = 0; k < 9; ++k) acc = fmaf(p[k], w[co * 9 + k], acc);
      o[e] = (f16)(acc > 0.f ? acc : 0.01f * acc);
    }
    *(f16x8*)(op + c8 * 8) = o;
  }
}

__device__ __forceinline__ void dev_conv_cl(
    const float* __restrict__ in, const float* __restrict__ w,
    const float* __restrict__ b, f16* __restrict__ out, int H, int id) {
  int total = NB * H * H;
  if (id >= total) return;
  int x = id % H;
  int t = id / H;
  int y = t % H;
  int n = t / H;
  f16* op = out + (size_t)id * MID;
  const float* ip = in + (size_t)n * H * H;
  float p[9];
#pragma unroll
  for (int dy = 0; dy < 3; ++dy)
#pragma unroll
    for (int dx = 0; dx < 3; ++dx) {
      int yy = y + dy - 1, xx = x + dx - 1;
      p[dy * 3 + dx] = (yy >= 0 && yy < H && xx >= 0 && xx < H)
                           ? ip[(size_t)yy * H + xx] : 0.f;
    }
#pragma unroll
  for (int c8 = 0; c8 < 8; ++c8) {
    f16x8 o;
#pragma unroll
    for (int e = 0; e < 8; ++e) {
      int co = c8 * 8 + e;
      float acc = b[co];
#pragma unroll
      for (int k = 0; k < 9; ++k) acc = fmaf(p[k], w[co * 9 + k], acc);
      o[e] = (f16)(acc > 0.f ? acc : 0.01f * acc);
    }
    *(f16x8*)(op + c8 * 8) = o;
  }
}

__device__ __forceinline__ void dev_conv8x8(
    const float* __restrict__ in, const float* __restrict__ w,
    const float* __restrict__ b, float* __restrict__ out, int H, int W,
    int id) {
  int total = NB * H * W;
  if (id >= total) return;
  int x = id % W;
  int t = id / W;
  int y = t % H;
  int n = t / H;
  const float* ip = in + (size_t)n * BAND * H * W;
  float p[BAND][9];
#pragma unroll
  for (int ci = 0; ci < BAND; ++ci)
#pragma unroll
    for (int dy = 0; dy < 3; ++dy)
#pragma unroll
      for (int dx = 0; dx < 3; ++dx) {
        int yy = y + dy - 1, xx = x + dx - 1;
        p[ci][dy * 3 + dx] = (yy >= 0 && yy < H && xx >= 0 && xx < W)
                                 ? ip[((size_t)ci * H + yy) * W + xx] : 0.f;
      }
  float* op = out + ((size_t)n * BAND * H + y) * W + x;
  for (int co = 0; co < BAND; ++co) {
    float acc = b[co];
#pragma unroll
    for (int ci = 0; ci < BAND; ++ci)
#pragma unroll
      for (int k = 0; k < 9; ++k)
        acc = fmaf(p[ci][k], w[(co * BAND + ci) * 9 + k], acc);
    acc = acc > 0.f ? acc : 0.01f * acc;
    op[(size_t)co * H * W] = acc;
  }
}

// ------------- packed input convs: q (1168) | k (72) | v (72) ---------------
__global__ __launch_bounds__(256) void csa_convs(
    const float* __restrict__ pan, const float* __restrict__ wq,
    const float* __restrict__ bq, f16* __restrict__ qps,
    const float* __restrict__ pan2, const float* __restrict__ wk,
    const float* __restrict__ bk, f16* __restrict__ kcl,
    const float* __restrict__ ms, const float* __restrict__ wv,
    const float* __restrict__ bv, float* __restrict__ v_fea) {
  const int bid = blockIdx.x;
  const int tid = threadIdx.x;
  if (bid < NBQ) {
    dev_convq(pan, wq, bq, qps, bid * 256 + tid);
  } else if (bid < NBQ + NBC) {
    dev_conv_cl(pan2, wk, bk, kcl, HK, (bid - NBQ) * 256 + tid);
  } else {
    dev_conv8x8(ms, wv, bv, v_fea, HK, HK, (bid - NBQ - NBC) * 256 + tid);
  }
}

// ---- patches: Kmat[l][(kh,kw,c)] f16 (rows>=576 zero), Vt[m][l], norms² ----
__global__ __launch_bounds__(256) void csa_build_patches(
    const f16* __restrict__ kcl, const float* __restrict__ v_fea,
    f16* __restrict__ Kmat, f16* __restrict__ Vt, float* __restrict__ n2) {
  int blk = blockIdx.x;  // NB*LP blocks
  int n = blk / LP;
  int l = blk % LP;
  int tid = threadIdx.x;
  f16* krow = Kmat + ((size_t)n * LP + l) * KDIM;
  if (l >= L) {
    f16x8 z = {0, 0, 0, 0, 0, 0, 0, 0};
    for (int ch = tid; ch < 200; ch += 256) *(f16x8*)(krow + ch * 8) = z;
    return;
  }
  int i = l / LN, j = l % LN;
  const f16* kn = kcl + (size_t)n * HK * HK * MID;
  float ss = 0.f;
  for (int ch = tid; ch < 200; ch += 256) {
    int khkw = ch >> 3;
    int c0 = (ch & 7) * 8;
    int kh = khkw / 5, kw = khkw % 5;
    int r = (4 * i + kh + 95) % 97;
    int cc = (4 * j + kw + 95) % 97;
    f16x8 v = {0, 0, 0, 0, 0, 0, 0, 0};
    if (r < HK && cc < HK)
      v = *(const f16x8*)(kn + ((size_t)r * HK + cc) * MID + c0);
#pragma unroll
    for (int e = 0; e < 8; ++e) {
      float fv = (float)v[e];
      ss += fv * fv;
    }
    *(f16x8*)(krow + ch * 8) = v;
  }
  for (int m = tid; m < MV; m += 256) {
    float v = 0.f;
    if (m < VDIM) {
      int kw = m % 5;
      int t = m / 5;
      int kh = t % 5;
      int c = t / 5;
      int r = (4 * i + kh + 95) % 97;
      int cc = (4 * j + kw + 95) % 97;
      v = (r < HK && cc < HK)
              ? v_fea[(((size_t)n * BAND + c) * HK + r) * HK + cc] : 0.f;
    }
    Vt[((size_t)n * MV + m) * L + l] = (f16)v;
  }
  __shared__ float red[256];
  red[tid] = ss;
  __syncthreads();
  for (int s = 128; s > 0; s >>= 1) {
    if (tid < s) red[tid] += red[tid + s];
    __syncthreads();
  }
  if (tid == 0) n2[n * L + l] = red[0];
}

// ---------------- scale[n] = 10 / sqrt(max_l norms2[n][l]) ------------------
__global__ __launch_bounds__(256) void csa_max_scale(
    const float* __restrict__ n2, float* __restrict__ scale) {
  int n = blockIdx.x;
  int tid = threadIdx.x;
  float m = 0.f;
  for (int l = tid; l < L; l += 256) m = fmaxf(m, n2[n * L + l]);
  __shared__ float red[256];
  red[tid] = m;
  __syncthreads();
  for (int s = 128; s > 0; s >>= 1) {
    if (tid < s) red[tid] = fmaxf(red[tid], red[tid + s]);
    __syncthreads();
  }
  if (tid == 0) scale[n] = 10.f / sqrtf(red[0]);
}

// --------------------------- MFMA GEMM helpers ------------------------------
__device__ __forceinline__ void gl_lds16(const f16* g, f16* s) {
  __builtin_amdgcn_global_load_lds(
      (const __attribute__((address_space(1))) void*)g,
      (__attribute__((address_space(3))) void*)s, 16, 0, 0);
}

// ------------- GEMM1: scoresT[p][l] = implicit-Q  x  Kmat^T -----------------
// v8 schedule: 512 threads / 8 waves (4M x 2N, per-wave 32x64, acc[2][4]).
// BK=64 = one (kh,kw) plane per K-tile (25 tiles). LDS: A/B each
// [2 buf][8 groups][2 khalf][512 f16] = 16KB x4 = 64KB -> 2 blocks/CU
// (launch_bounds(512,4) caps VGPR at 128 -> 16 waves/CU).
// Per tile: counted vmcnt(4) (tile t landed, t+1 in flight) + barrier;
// two kk-phases {6x ds_read_b128, setprio(1), 8 MFMA, setprio(0)};
// barrier; stage(t+2) into the buffer just freed. Drain-0 only at t=24.
// Per-lane fragment math identical to v7 (proven).
__global__ __launch_bounds__(512, 4) void csa_gemm1(
    const f16* __restrict__ qps, const f16* __restrict__ Km,
    float* __restrict__ C) {
  __shared__ __attribute__((aligned(16))) f16 As[2][8192];
  __shared__ __attribute__((aligned(16))) f16 Bs[2][8192];
  const int tid = threadIdx.x;
  const int w = tid >> 6;          // 0..7
  const int l = tid & 63;
  const int q = l >> 4;
  const int r = l & 15;

  // bijective XCD-chunk swizzle: nwg=720, 720%8==0, chunk=90
  const int flat = blockIdx.x + 5 * (blockIdx.y + 72 * blockIdx.z);
  const int logical = (flat & 7) * 90 + (flat >> 3);
  const int bx = logical % 5;
  const int by = (logical / 5) % 72;
  const int nb = logical / 360;

  qps += (size_t)nb * QPSN;
  Km += (size_t)nb * LP * KDIM;
  C += (size_t)nb * (size_t)PS * L;
  const int bm = by * 128;
  const int bn = bx * 128;
  const int wmw = (w >> 1) * 32;   // wave M offset (4 M-waves)
  const int wnw = (w & 1) * 64;    // wave N offset (2 N-waves)

  f32x4 acc[2][4];
#pragma unroll
  for (int i = 0; i < 2; ++i)
#pragma unroll
    for (int j = 0; j < 4; ++j) {
      f32x4 z = {0.f, 0.f, 0.f, 0.f};
      acc[i][j] = z;
    }

  // staging: wave w stages A row-group w and B n-group w (16 rows each).
  const int pg0 = bm + w * 16;            // multiple of 16; same y for 16 rows
  const int y0 = pg0 / 96, x0 = pg0 % 96;
  const int la = r * MID + q * 8;         // lane offset in f16
  const f16* gb = Km + (size_t)(bn + w * 16 + r) * KDIM + q * 8;

  auto stage = [&](int t, int c) {
    const int kh = t / 5, kw = t - kh * 5;
    const size_t u0 =
        (((size_t)(kw & 3) * HQP + (4 * y0 + kh)) * XI + x0 + (kw >> 2)) * MID +
        la;
    const f16* gk = gb + (size_t)t * 64;
    f16* dA = &As[c][(w * 2) * 512];
    f16* dB = &Bs[c][(w * 2) * 512];
    gl_lds16(qps + u0, dA);           // A kk=0
    gl_lds16(qps + u0 + 32, dA + 512);// A kk=1
    gl_lds16(gk, dB);                 // B kk=0
    gl_lds16(gk + 32, dB + 512);      // B kk=1
  };

  const int ag = (w >> 1) * 2;       // af group base (rows wmw..wmw+31)
  const int bg = (w & 1) * 4;        // bf group base (cols wnw..wnw+63)
  const int lo = q * 128 + r * 8;    // lane offset within a 512-f16 slab
  auto phase = [&](int c, int kk) {
    f16x8 af[2], bf[4];
#pragma unroll
    for (int u = 0; u < 2; ++u)
      af[u] = *(const f16x8*)&As[c][((ag + u) * 2 + kk) * 512 + lo];
#pragma unroll
    for (int j = 0; j < 4; ++j)
      bf[j] = *(const f16x8*)&Bs[c][((bg + j) * 2 + kk) * 512 + lo];
    __builtin_amdgcn_s_setprio(1);
#pragma unroll
    for (int i = 0; i < 2; ++i)
#pragma unroll
      for (int j = 0; j < 4; ++j)
        acc[i][j] = __builtin_amdgcn_mfma_f32_16x16x32_f16(af[i], bf[j],
                                                           acc[i][j], 0, 0, 0);
    __builtin_amdgcn_s_setprio(0);
  };

  stage(0, 0);
  stage(1, 1);
  for (int t = 0; t < 24; ++t) {
    const int c = t & 1;
    asm volatile("s_waitcnt vmcnt(4)" ::: "memory");  // tile t landed
    __builtin_amdgcn_s_barrier();
    __builtin_amdgcn_sched_barrier(0);
    phase(c, 0);
    phase(c, 1);
    __builtin_amdgcn_sched_barrier(0);
    __builtin_amdgcn_s_barrier();                     // buf c free
    if (t < 23) stage(t + 2, c);
  }
  asm volatile("s_waitcnt vmcnt(0)" ::: "memory");    // tile 24 landed
  __builtin_amdgcn_s_barrier();
  __builtin_amdgcn_sched_barrier(0);
  phase(0, 0);   // tile 24 is in buf 0 (24&1==0)
  phase(0, 1);

  // C row stride L (=576); guard drops the 64 pad columns.
  const int cn = bn + wnw + r;
#pragma unroll
  for (int i = 0; i < 2; ++i) {
    int rm = bm + wmw + i * 16 + q * 4;
#pragma unroll
    for (int j = 0; j < 4; ++j) {
      int cc = cn + j * 16;
      if (cc < L) {
#pragma unroll
        for (int rr = 0; rr < 4; ++rr)
          C[(size_t)(rm + rr) * L + cc] = acc[i][j][rr];
      }
    }
  }
}

// --------------- GEMM2: D[m][p] = Vt[m][l] x attnT[p][l]^T ------------------
// 64(M) x 128(N) tile, 4 waves as 2Mx2N (per-wave 32x64), 3-buffer
// counted-vmcnt LDS pipeline. Grid 72x4x2 = 576 blocks.
__global__ __launch_bounds__(256) void csa_gemm2(
    const f16* __restrict__ Vt, const f16* __restrict__ At,
    float* __restrict__ D) {
  __shared__ __attribute__((aligned(16))) f16 As[3 * 2048];
  __shared__ __attribute__((aligned(16))) f16 Bs[3 * 4096];
  const int tid = threadIdx.x;
  const int w = tid >> 6;
  const int l = tid & 63;
  const int q = l >> 4;
  const int r = l & 15;

  // bijective XCD-chunk swizzle: nwg=576, chunk=72; nx fast -> same-A blocks
  // adjacent on one XCD.
  const int flat = blockIdx.x + 72 * (blockIdx.y + 4 * blockIdx.z);
  const int logical = (flat & 7) * 72 + (flat >> 3);
  const int nx = logical % 72;
  const int my = (logical / 72) % 4;
  const int nb = logical / 288;

  const f16* A = Vt + (size_t)nb * MV * L;
  const f16* Bt = At + (size_t)nb * (size_t)PS * L;
  float* C = D + (size_t)nb * (size_t)MV * PS;
  const int bm = my * 64;
  const int bn = nx * 128;
  const int wm = (w >> 1) * 32;
  const int wn = (w & 1) * 64;

  f32x4 acc[2][4];
#pragma unroll
  for (int i = 0; i < 2; ++i)
#pragma unroll
    for (int j = 0; j < 4; ++j) {
      f32x4 z = {0.f, 0.f, 0.f, 0.f};
      acc[i][j] = z;
    }

  const f16* ga  = A + (size_t)(bm + w * 16 + r) * L + q * 8;
  const f16* gb0 = Bt + (size_t)(bn + w * 16 + r) * L + q * 8;
  const f16* gb1 = gb0 + (size_t)64 * L;
  const int am = (w >> 1) * 2;
  const int bnn = (w & 1) * 4;

  auto stage = [&](int t, int bi) {
    f16* bA = As + bi * 2048;
    f16* bB = Bs + bi * 4096;
    const size_t k0 = (size_t)t * 32;
    gl_lds16(ga + k0, bA + w * 512);
    gl_lds16(gb0 + k0, bB + w * 512);
    gl_lds16(gb1 + k0, bB + 2048 + w * 512);
  };
  auto compute = [&](int bi) {
    const f16* bA = As + bi * 2048;
    const f16* bB = Bs + bi * 4096;
    f16x8 af[2], bf[4];
#pragma unroll
    for (int u = 0; u < 2; ++u)
      af[u] = *(const f16x8*)&bA[(am + u) * 512 + q * 128 + r * 8];
#pragma unroll
    for (int u = 0; u < 4; ++u)
      bf[u] = *(const f16x8*)&bB[(bnn + u) * 512 + q * 128 + r * 8];
#pragma unroll
    for (int i = 0; i < 2; ++i)
#pragma unroll
      for (int j = 0; j < 4; ++j)
        acc[i][j] = __builtin_amdgcn_mfma_f32_16x16x32_f16(af[i], bf[j],
                                                           acc[i][j], 0, 0, 0);
  };

  // NT = 18 K-steps of 32. 3 loads per stage -> counted vmcnt(3).
  stage(0, 0);
  stage(1, 1);
  int bi = 0;
  for (int t = 0; t < 16; ++t) {
    asm volatile("s_waitcnt vmcnt(3)" ::: "memory");  // stage(t) landed
    __builtin_amdgcn_s_barrier();
    __builtin_amdgcn_sched_barrier(0);
    stage(t + 2, bi == 0 ? 2 : bi - 1);
    compute(bi);
    bi = (bi == 2) ? 0 : bi + 1;
  }
  asm volatile("s_waitcnt vmcnt(3)" ::: "memory");    // stage(16) landed
  __builtin_amdgcn_s_barrier();
  __builtin_amdgcn_sched_barrier(0);
  compute(bi);
  bi = (bi == 2) ? 0 : bi + 1;
  asm volatile("s_waitcnt vmcnt(0)" ::: "memory");    // stage(17) landed
  __builtin_amdgcn_s_barrier();
  __builtin_amdgcn_sched_barrier(0);
  compute(bi);

  const int cn = bn + wn + r;
#pragma unroll
  for (int i = 0; i < 2; ++i) {
    int rm = bm + wm + i * 16 + q * 4;
#pragma unroll
    for (int j = 0; j < 4; ++j)
#pragma unroll
      for (int rr = 0; rr < 4; ++rr)
        C[(size_t)(rm + rr) * PS + cn + j * 16] = acc[i][j][rr];
  }
}

// ------- row softmax: attnT[p][l] f16 = softmax_l(scoresT[p][l]*scale) ------
__global__ __launch_bounds__(256) void csa_softmax(
    const float* __restrict__ scoresT, const float* __restrict__ scale,
    f16* __restrict__ attnT) {
  const int wv = threadIdx.x >> 6;
  const int lane = threadIdx.x & 63;
  const int p = blockIdx.x * 4 + wv;
  const int n = blockIdx.y;
  const float sc = scale[n];
  const float* row = scoresT + ((size_t)n * PS + p) * L;
  float v[9];
  float m = -1e30f;
#pragma unroll
  for (int j = 0; j < 9; ++j) {
    v[j] = row[lane + j * 64] * sc;
    m = fmaxf(m, v[j]);
  }
#pragma unroll
  for (int off = 32; off > 0; off >>= 1) m = fmaxf(m, __shfl_xor(m, off));
  float e[9], s = 0.f;
#pragma unroll
  for (int j = 0; j < 9; ++j) {
    e[j] = __expf(v[j] - m);
    s += e[j];
  }
#pragma unroll
  for (int off = 32; off > 0; off >>= 1) s += __shfl_xor(s, off);
  const float inv = 1.f / s;
  f16* orow = attnT + ((size_t)n * PS + p) * L;
#pragma unroll
  for (int j = 0; j < 9; ++j) orow[lane + j * 64] = (f16)(e[j] * inv);
}

// ------ fused: res = gather(D)/6 (LDS tile) -> conv3 8x8 -> out -------------
__global__ __launch_bounds__(256) void csa_gather_conv(
    const float* __restrict__ D, const float* __restrict__ wr,
    const float* __restrict__ br, float* __restrict__ out) {
  __shared__ float rs[BAND][18][18];
  __shared__ float wsm[BAND * BAND * 9];
  __shared__ float brs[BAND];
  const int tid = threadIdx.x;
  const int n = blockIdx.z;
  const int ty = blockIdx.y, tx = blockIdx.x;
  const float* Dn = D + (size_t)n * MV * PS;

  for (int i = tid; i < BAND * BAND * 9; i += 256) wsm[i] = wr[i];
  if (tid < BAND) brs[tid] = br[tid];

  for (int idx = tid; idx < BAND * 18 * 18; idx += 256) {
    int ci = idx / 324;
    int rem = idx - ci * 324;
    int yy = rem / 18;
    int xx = rem - yy * 18;
    int oy = ty * 16 - 1 + yy;
    int ox = tx * 16 - 1 + xx;
    float s = 0.f;
    if (oy >= 0 && oy < HO && ox >= 0 && ox < HO) {
      int kh0 = oy & 3;
      int kw0 = ox & 3;
      for (int kh = kh0; kh < 5; kh += 4) {
        int y = (oy - kh) >> 2;
        if (y < 0 || y >= 96) continue;
        for (int kw = kw0; kw < 5; kw += 4) {
          int x = (ox - kw) >> 2;
          if (x < 0 || x >= 96) continue;
          s += Dn[(size_t)(ci * 25 + kh * 5 + kw) * PS + y * 96 + x];
        }
      }
      s *= (1.f / 6.f);
    }
    rs[ci][yy][xx] = s;
  }
  __syncthreads();

  const int y = tid >> 4, x = tid & 15;
  const int oy = ty * 16 + y, ox = tx * 16 + x;
  if (oy >= HO || ox >= HO) return;
  float p[BAND][9];
#pragma unroll
  for (int ci = 0; ci < BAND; ++ci)
#pragma unroll
    for (int dy = 0; dy < 3; ++dy)
#pragma unroll
      for (int dx = 0; dx < 3; ++dx)
        p[ci][dy * 3 + dx] = rs[ci][y + dy][x + dx];
  float* op = out + ((size_t)n * BAND * HO + oy) * HO + ox;
  for (int co = 0; co < BAND; ++co) {
    float acc = brs[co];
#pragma unroll
    for (int ci = 0; ci < BAND; ++ci)
#pragma unroll
      for (int k = 0; k < 9; ++k)
        acc = fmaf(p[ci][k], wsm[(co * BAND + ci) * 9 + k], acc);
    acc = acc > 0.f ? acc : 0.01f * acc;
    op[(size_t)co * HO * HO] = acc;
  }
}

// ---------------------------------------------------------------------------
extern "C" void kernel_launch(void* const* d_in, const int* in_sizes, int n_in,
                              void* d_out, int out_size, void* d_ws,
                              size_t ws_size, hipStream_t stream) {
  const float* ms   = (const float*)d_in[0];
  const float* pan  = (const float*)d_in[1];
  const float* pan2 = (const float*)d_in[2];
  const float* wq = (const float*)d_in[3];
  const float* bq = (const float*)d_in[4];
  const float* wk = (const float*)d_in[5];
  const float* bk = (const float*)d_in[6];
  const float* wv = (const float*)d_in[7];
  const float* bv = (const float*)d_in[8];
  const float* wr = (const float*)d_in[9];
  const float* br = (const float*)d_in[10];
  float* out = (float*)d_out;

  char* ws = (char*)d_ws;
  f16*   qps   = (f16*)(ws + OFF_QPS);
  f16*   kcl   = (f16*)(ws + OFF_KCL);
  float* v_fea = (float*)(ws + OFF_VFEA);
  float* n2    = (float*)(ws + OFF_N2);
  float* scale = (float*)(ws + OFF_SC);
  f16*   Kmat  = (f16*)(ws + OFF_KM);
  f16*   Vt    = (f16*)(ws + OFF_VT);
  float* scoT  = (float*)(ws + OFF_ST);
  f16*   attnT = (f16*)(ws + OFF_AT);
  float* Dm    = (float*)(ws + OFF_D);

  dim3 b256(256);
  csa_convs<<<dim3(NBQ + 2 * NBC), b256, 0, stream>>>(
      pan, wq, bq, qps, pan2, wk, bk, kcl, ms, wv, bv, v_fea);
  csa_build_patches<<<dim3(NB * LP), b256, 0, stream>>>(kcl, v_fea, Kmat, Vt,
                                                        n2);
  csa_max_scale<<<dim3(NB), b256, 0, stream>>>(n2, scale);

  // GEMM1: scoresT[PS][L] = implicit-Q x Kmat^T (512 threads, 8 waves)
  csa_gemm1<<<dim3(LP / 128, PS / 128, NB), dim3(512), 0, stream>>>(qps, Kmat,
                                                                    scoT);

  csa_softmax<<<dim3(PS / 4, NB), b256, 0, stream>>>(scoT, scale, attnT);

  // GEMM2: D[MV][PS] = Vt[MV][L] x attnT[PS][L]^T (64x128 tiles)
  csa_gemm2<<<dim3(PS / 128, MV / 64, NB), b256, 0, stream>>>(Vt, attnT, Dm);

  // fused gather + final conv3 8x8 -> out
  csa_gather_conv<<<dim3((HO + 15) / 16, (HO + 15) / 16, NB), b256, 0,
                    stream>>>(Dm, wr, br, out);
}

// Round 5
// 271.508 us; speedup vs baseline: 1.0403x; 1.0403x over previous
//
#include <hip/hip_runtime.h>
#include <math.h>

// ---------------------------------------------------------------------------
// cross_scale_attention v9: v7 (proven GEMM1) + GEMM2 swizzle polarity fix
// (my-fastest: blocks sharing one attnT B-tile run adjacent on one XCD).
//   qps[n][f][385][97][64] f16 <- conv3(pan, wq, bq); entry (f,y',xi) = pixel
//        (y', 4*xi+f), zero if y'>=384 or 4*xi+f>=384  (SAME-pad)
//   kcl[n][96][96][64]   f16 <- conv3(pan2, wk, bk), channels-last
//   v_fea fp32           <- conv3(ms, wv, bv)
//   Kmat[n][l][(kh,kw,c)] f16 (640 rows, pad 0) + norms  <- kcl gather
//   Vt[n][m][l] f16 (256x576)
//   scoresT[n][p][l576] = implicit-Q x Kmat^T   (MFMA GEMM1, A from qps)
//   attnT[n][p][l] f16  = softmax * 10/maxnorm
//   D[n][m][p] = Vt x attnT^T                   (MFMA GEMM2, 64x128 tile)
//   out = conv3_8x8(gather(D)/6)  (fused, res tile staged in LDS)
// ---------------------------------------------------------------------------

typedef _Float16 f16;
typedef _Float16 f16x8 __attribute__((ext_vector_type(8)));
typedef float f32x4 __attribute__((ext_vector_type(4)));

namespace csa {
constexpr int NB   = 2;
constexpr int MID  = 64;
constexpr int BAND = 8;
constexpr int HK   = 96;
constexpr int HQ   = 384;
constexpr int HQP  = 385;
constexpr int XI   = 97;            // xi range per phase
constexpr int LN   = 24;
constexpr int L    = 576;
constexpr int LP   = 640;
constexpr int PS   = 96 * 96;       // 9216
constexpr int KDIM = MID * 25;      // 1600
constexpr int VDIM = BAND * 25;     // 200
constexpr int MV   = 256;
constexpr int HO   = 385;
constexpr size_t QPSN = (size_t)4 * HQP * XI * MID;  // per-batch qps elems

constexpr int NBQ = (NB * 4 * HQP * XI + 255) / 256;  // 1168 conv-q blocks
constexpr int NBC = NB * HK * HK / 256;               // 72 blocks each

constexpr size_t align256(size_t x) { return (x + 255) & ~(size_t)255; }
constexpr size_t OFF_QPS  = 0;                                            // f16 NB*QPSN
constexpr size_t OFF_KCL  = align256(OFF_QPS + (size_t)NB*QPSN*2);        // f16 NB*96*96*64
constexpr size_t OFF_VFEA = align256(OFF_KCL + (size_t)NB*HK*HK*MID*2);   // f32 NB*8*96*96
constexpr size_t OFF_N2   = align256(OFF_VFEA + (size_t)NB*BAND*HK*HK*4);
constexpr size_t OFF_SC   = align256(OFF_N2   + (size_t)NB*L*4);
constexpr size_t OFF_KM   = align256(OFF_SC   + 256);                     // f16 NB*640*1600
constexpr size_t OFF_VT   = align256(OFF_KM   + (size_t)NB*LP*KDIM*2);    // f16 NB*256*576
constexpr size_t OFF_ST   = align256(OFF_VT   + (size_t)NB*MV*L*2);      // f32 NB*9216*576
constexpr size_t OFF_AT   = align256(OFF_ST   + (size_t)NB*PS*LP*4);      // f16 NB*9216*576
constexpr size_t OFF_D    = align256(OFF_AT   + (size_t)NB*PS*L*2);       // f32 NB*256*9216
}  // namespace csa
using namespace csa;

// ----------------------------- conv device bodies ---------------------------
__device__ __forceinline__ void dev_convq(
    const float* __restrict__ in, const float* __restrict__ w,
    const float* __restrict__ b, f16* __restrict__ out, int id) {
  int total = NB * 4 * HQP * XI;
  if (id >= total) return;
  int xi = id % XI;
  int t = id / XI;
  int yp = t % HQP;
  t /= HQP;
  int f = t % 4;
  int n = t / 4;
  int xp = 4 * xi + f;
  f16* op = out + (size_t)id * MID;
  if (yp >= HQ || xp >= HQ) {
    f16x8 z = {0, 0, 0, 0, 0, 0, 0, 0};
#pragma unroll
    for (int c8 = 0; c8 < 8; ++c8) *(f16x8*)(op + c8 * 8) = z;
    return;
  }
  const float* ip = in + (size_t)n * HQ * HQ;
  float p[9];
#pragma unroll
  for (int dy = 0; dy < 3; ++dy)
#pragma unroll
    for (int dx = 0; dx < 3; ++dx) {
      int yy = yp + dy - 1, xx = xp + dx - 1;
      p[dy * 3 + dx] = (yy >= 0 && yy < HQ && xx >= 0 && xx < HQ)
                           ? ip[(size_t)yy * HQ + xx] : 0.f;
    }
#pragma unroll
  for (int c8 = 0; c8 < 8; ++c8) {
    f16x8 o;
#pragma unroll
    for (int e = 0; e < 8; ++e) {
      int co = c8 * 8 + e;
      float acc = b[co];
#pragma unroll
      for (int k = 0; k < 9; ++k) acc = fmaf(p[k], w[co * 9 + k], acc);
      o[e] = (f16)(acc > 0.f ? acc : 0.01f * acc);
    }
    *(f16x8*)(op + c8 * 8) = o;
  }
}

__device__ __forceinline__ void dev_conv_cl(
    const float* __restrict__ in, const float* __restrict__ w,
    const float* __restrict__ b, f16* __restrict__ out, int H, int id) {
  int total = NB * H * H;
  if (id >= total) return;
  int x = id % H;
  int t = id / H;
  int y = t % H;
  int n = t / H;
  f16* op = out + (size_t)id * MID;
  const float* ip = in + (size_t)n * H * H;
  float p[9];
#pragma unroll
  for (int dy = 0; dy < 3; ++dy)
#pragma unroll
    for (int dx = 0; dx < 3; ++dx) {
      int yy = y + dy - 1, xx = x + dx - 1;
      p[dy * 3 + dx] = (yy >= 0 && yy < H && xx >= 0 && xx < H)
                           ? ip[(size_t)yy * H + xx] : 0.f;
    }
#pragma unroll
  for (int c8 = 0; c8 < 8; ++c8) {
    f16x8 o;
#pragma unroll
    for (int e = 0; e < 8; ++e) {
      int co = c8 * 8 + e;
      float acc = b[co];
#pragma unroll
      for (int k = 0; k < 9; ++k) acc = fmaf(p[k], w[co * 9 + k], acc);
      o[e] = (f16)(acc > 0.f ? acc : 0.01f * acc);
    }
    *(f16x8*)(op + c8 * 8) = o;
  }
}

__device__ __forceinline__ void dev_conv8x8(
    const float* __restrict__ in, const float* __restrict__ w,
    const float* __restrict__ b, float* __restrict__ out, int H, int W,
    int id) {
  int total = NB * H * W;
  if (id >= total) return;
  int x = id % W;
  int t = id / W;
  int y = t % H;
  int n = t / H;
  const float* ip = in + (size_t)n * BAND * H * W;
  float p[BAND][9];
#pragma unroll
  for (int ci = 0; ci < BAND; ++ci)
#pragma unroll
    for (int dy = 0; dy < 3; ++dy)
#pragma unroll
      for (int dx = 0; dx < 3; ++dx) {
        int yy = y + dy - 1, xx = x + dx - 1;
        p[ci][dy * 3 + dx] = (yy >= 0 && yy < H && xx >= 0 && xx < W)
                                 ? ip[((size_t)ci * H + yy) * W + xx] : 0.f;
      }
  float* op = out + ((size_t)n * BAND * H + y) * W + x;
  for (int co = 0; co < BAND; ++co) {
    float acc = b[co];
#pragma unroll
    for (int ci = 0; ci < BAND; ++ci)
#pragma unroll
      for (int k = 0; k < 9; ++k)
        acc = fmaf(p[ci][k], w[(co * BAND + ci) * 9 + k], acc);
    acc = acc > 0.f ? acc : 0.01f * acc;
    op[(size_t)co * H * W] = acc;
  }
}

// ------------- packed input convs: q (1168) | k (72) | v (72) ---------------
__global__ __launch_bounds__(256) void csa_convs(
    const float* __restrict__ pan, const float* __restrict__ wq,
    const float* __restrict__ bq, f16* __restrict__ qps,
    const float* __restrict__ pan2, const float* __restrict__ wk,
    const float* __restrict__ bk, f16* __restrict__ kcl,
    const float* __restrict__ ms, const float* __restrict__ wv,
    const float* __restrict__ bv, float* __restrict__ v_fea) {
  const int bid = blockIdx.x;
  const int tid = threadIdx.x;
  if (bid < NBQ) {
    dev_convq(pan, wq, bq, qps, bid * 256 + tid);
  } else if (bid < NBQ + NBC) {
    dev_conv_cl(pan2, wk, bk, kcl, HK, (bid - NBQ) * 256 + tid);
  } else {
    dev_conv8x8(ms, wv, bv, v_fea, HK, HK, (bid - NBQ - NBC) * 256 + tid);
  }
}

// ---- patches: Kmat[l][(kh,kw,c)] f16 (rows>=576 zero), Vt[m][l], norms² ----
__global__ __launch_bounds__(256) void csa_build_patches(
    const f16* __restrict__ kcl, const float* __restrict__ v_fea,
    f16* __restrict__ Kmat, f16* __restrict__ Vt, float* __restrict__ n2) {
  int blk = blockIdx.x;  // NB*LP blocks
  int n = blk / LP;
  int l = blk % LP;
  int tid = threadIdx.x;
  f16* krow = Kmat + ((size_t)n * LP + l) * KDIM;
  if (l >= L) {
    f16x8 z = {0, 0, 0, 0, 0, 0, 0, 0};
    for (int ch = tid; ch < 200; ch += 256) *(f16x8*)(krow + ch * 8) = z;
    return;
  }
  int i = l / LN, j = l % LN;
  const f16* kn = kcl + (size_t)n * HK * HK * MID;
  float ss = 0.f;
  for (int ch = tid; ch < 200; ch += 256) {
    int khkw = ch >> 3;
    int c0 = (ch & 7) * 8;
    int kh = khkw / 5, kw = khkw % 5;
    int r = (4 * i + kh + 95) % 97;
    int cc = (4 * j + kw + 95) % 97;
    f16x8 v = {0, 0, 0, 0, 0, 0, 0, 0};
    if (r < HK && cc < HK)
      v = *(const f16x8*)(kn + ((size_t)r * HK + cc) * MID + c0);
#pragma unroll
    for (int e = 0; e < 8; ++e) {
      float fv = (float)v[e];
      ss += fv * fv;
    }
    *(f16x8*)(krow + ch * 8) = v;
  }
  for (int m = tid; m < MV; m += 256) {
    float v = 0.f;
    if (m < VDIM) {
      int kw = m % 5;
      int t = m / 5;
      int kh = t % 5;
      int c = t / 5;
      int r = (4 * i + kh + 95) % 97;
      int cc = (4 * j + kw + 95) % 97;
      v = (r < HK && cc < HK)
              ? v_fea[(((size_t)n * BAND + c) * HK + r) * HK + cc] : 0.f;
    }
    Vt[((size_t)n * MV + m) * L + l] = (f16)v;
  }
  __shared__ float red[256];
  red[tid] = ss;
  __syncthreads();
  for (int s = 128; s > 0; s >>= 1) {
    if (tid < s) red[tid] += red[tid + s];
    __syncthreads();
  }
  if (tid == 0) n2[n * L + l] = red[0];
}

// ---------------- scale[n] = 10 / sqrt(max_l norms2[n][l]) ------------------
__global__ __launch_bounds__(256) void csa_max_scale(
    const float* __restrict__ n2, float* __restrict__ scale) {
  int n = blockIdx.x;
  int tid = threadIdx.x;
  float m = 0.f;
  for (int l = tid; l < L; l += 256) m = fmaxf(m, n2[n * L + l]);
  __shared__ float red[256];
  red[tid] = m;
  __syncthreads();
  for (int s = 128; s > 0; s >>= 1) {
    if (tid < s) red[tid] = fmaxf(red[tid], red[tid + s]);
    __syncthreads();
  }
  if (tid == 0) scale[n] = 10.f / sqrtf(red[0]);
}

// --------------------------- MFMA GEMM helpers ------------------------------
__device__ __forceinline__ void gl_lds16(const f16* g, f16* s) {
  __builtin_amdgcn_global_load_lds(
      (const __attribute__((address_space(1))) void*)g,
      (__attribute__((address_space(3))) void*)s, 16, 0, 0);
}

// ------------- GEMM1: scoresT[p][l] = implicit-Q  x  Kmat^T -----------------
// A[p][k], k=(kh*5+kw)*64+c. A row p -> (y=p/96, x=p%96); element =
// qps[f=kw&3][4y+kh][x + (kw>>2)][c]. 16-lane groups have fixed y (96%16==0),
// so lane addr = uniform + r*128B + q*16B -> fully coalesced staging.
// XCD-chunk swizzle (720 wg = 90/XCD; bx fastest: 5 blocks sharing one
// 400KB qps A-panel run consecutively on one XCD) + 3-buffer 2-ahead
// pipeline, raw s_barrier + counted s_waitcnt vmcnt(4).
__global__ __launch_bounds__(256) void csa_gemm1(
    const f16* __restrict__ qps, const f16* __restrict__ Km,
    float* __restrict__ C) {
  __shared__ __attribute__((aligned(16))) f16 As[3 * 4096];
  __shared__ __attribute__((aligned(16))) f16 Bs[3 * 4096];
  const int tid = threadIdx.x;
  const int w = tid >> 6;
  const int l = tid & 63;
  const int q = l >> 4;
  const int r = l & 15;

  // bijective XCD-chunk swizzle: nwg=720, 720%8==0, chunk=90
  const int flat = blockIdx.x + 5 * (blockIdx.y + 72 * blockIdx.z);
  const int logical = (flat & 7) * 90 + (flat >> 3);
  const int bx = logical % 5;
  const int by = (logical / 5) % 72;
  const int nb = logical / 360;

  qps += (size_t)nb * QPSN;
  Km += (size_t)nb * LP * KDIM;
  C += (size_t)nb * (size_t)PS * L;
  const int bm = by * 128;
  const int bn = bx * 128;
  const int wm = (w >> 1) * 64;
  const int wn = (w & 1) * 64;

  f32x4 acc[4][4];
#pragma unroll
  for (int i = 0; i < 4; ++i)
#pragma unroll
    for (int j = 0; j < 4; ++j) {
      f32x4 z = {0.f, 0.f, 0.f, 0.f};
      acc[i][j] = z;
    }

  const int pg0 = bm + w * 16;            // wave-uniform, multiple of 16
  const int y0 = pg0 / 96, x0 = pg0 % 96;
  const int pg1 = pg0 + 64;
  const int y1 = pg1 / 96, x1 = pg1 % 96;
  const int la = r * MID + q * 8;         // lane offset in f16

  const f16* gb0 = Km + (size_t)(bn + w * 16 + r) * KDIM + q * 8;
  const f16* gb1 = gb0 + (size_t)64 * KDIM;
  const int am = (w >> 1) * 4;
  const int bnn = (w & 1) * 4;

  // stage K-tile t (t in [0,50): kh=t/10, kw=(t%10)>>1, half=t&1) into buf bi
  auto stage = [&](int t, int bi) {
    f16* bA = As + bi * 4096;
    f16* bB = Bs + bi * 4096;
    const int kh = t / 10;
    const int rem = t - kh * 10;
    const int kw = rem >> 1;
    const int half = rem & 1;
    const size_t u0 =
        (((size_t)(kw & 3) * HQP + (4 * y0 + kh)) * XI + x0 + (kw >> 2)) * MID;
    const size_t u1 =
        (((size_t)(kw & 3) * HQP + (4 * y1 + kh)) * XI + x1 + (kw >> 2)) * MID;
    const size_t oA = (size_t)half * 32 + la;
    gl_lds16(qps + u0 + oA, bA + w * 512);
    gl_lds16(qps + u1 + oA, bA + 2048 + w * 512);
    gl_lds16(gb0 + (size_t)t * 32, bB + w * 512);
    gl_lds16(gb1 + (size_t)t * 32, bB + 2048 + w * 512);
  };
  auto compute = [&](int bi) {
    const f16* bA = As + bi * 4096;
    const f16* bB = Bs + bi * 4096;
    f16x8 af[4], bf[4];
#pragma unroll
    for (int u = 0; u < 4; ++u) {
      af[u] = *(const f16x8*)&bA[(am + u) * 512 + q * 128 + r * 8];
      bf[u] = *(const f16x8*)&bB[(bnn + u) * 512 + q * 128 + r * 8];
    }
#pragma unroll
    for (int i = 0; i < 4; ++i)
#pragma unroll
      for (int j = 0; j < 4; ++j)
        acc[i][j] = __builtin_amdgcn_mfma_f32_16x16x32_f16(af[i], bf[j],
                                                           acc[i][j], 0, 0, 0);
  };

  stage(0, 0);
  stage(1, 1);
  int bi = 0;
  for (int t = 0; t < 48; ++t) {
    asm volatile("s_waitcnt vmcnt(4)" ::: "memory");  // stage(t) landed
    __builtin_amdgcn_s_barrier();
    __builtin_amdgcn_sched_barrier(0);
    stage(t + 2, bi == 0 ? 2 : bi - 1);               // issue-early
    compute(bi);
    bi = (bi == 2) ? 0 : bi + 1;
  }
  asm volatile("s_waitcnt vmcnt(4)" ::: "memory");    // stage(48) landed
  __builtin_amdgcn_s_barrier();
  __builtin_amdgcn_sched_barrier(0);
  compute(bi);
  bi = (bi == 2) ? 0 : bi + 1;
  asm volatile("s_waitcnt vmcnt(0)" ::: "memory");    // stage(49) landed
  __builtin_amdgcn_s_barrier();
  __builtin_amdgcn_sched_barrier(0);
  compute(bi);

  // C row stride L (=576); guard drops the 64 pad columns.
  const int cn = bn + wn + r;
#pragma unroll
  for (int i = 0; i < 4; ++i) {
    int rm = bm + wm + i * 16 + q * 4;
#pragma unroll
    for (int j = 0; j < 4; ++j) {
      int c = cn + j * 16;
      if (c < L) {
#pragma unroll
        for (int rr = 0; rr < 4; ++rr)
          C[(size_t)(rm + rr) * L + c] = acc[i][j][rr];
      }
    }
  }
}

// --------------- GEMM2: D[m][p] = Vt[m][l] x attnT[p][l]^T ------------------
// 64(M) x 128(N) tile, 4 waves as 2Mx2N (per-wave 32x64), 3-buffer
// counted-vmcnt LDS pipeline. Grid 72x4x2 = 576 blocks.
// v9 SWIZZLE FIX: my fastest within the XCD chunk -> the 4 blocks sharing
// one 147KB attnT B-tile run consecutively on ONE XCD (B served from its L2
// after first touch). A (Vt, 0.6MB) is L2-resident everywhere regardless.
__global__ __launch_bounds__(256) void csa_gemm2(
    const f16* __restrict__ Vt, const f16* __restrict__ At,
    float* __restrict__ D) {
  __shared__ __attribute__((aligned(16))) f16 As[3 * 2048];
  __shared__ __attribute__((aligned(16))) f16 Bs[3 * 4096];
  const int tid = threadIdx.x;
  const int w = tid >> 6;
  const int l = tid & 63;
  const int q = l >> 4;
  const int r = l & 15;

  // bijective XCD-chunk swizzle: nwg=576, chunk=72; my fastest.
  const int flat = blockIdx.x + 72 * (blockIdx.y + 4 * blockIdx.z);
  const int logical = (flat & 7) * 72 + (flat >> 3);
  const int my = logical % 4;
  const int nx = (logical / 4) % 72;
  const int nb = logical / 288;

  const f16* A = Vt + (size_t)nb * MV * L;
  const f16* Bt = At + (size_t)nb * (size_t)PS * L;
  float* C = D + (size_t)nb * (size_t)MV * PS;
  const int bm = my * 64;
  const int bn = nx * 128;
  const int wm = (w >> 1) * 32;
  const int wn = (w & 1) * 64;

  f32x4 acc[2][4];
#pragma unroll
  for (int i = 0; i < 2; ++i)
#pragma unroll
    for (int j = 0; j < 4; ++j) {
      f32x4 z = {0.f, 0.f, 0.f, 0.f};
      acc[i][j] = z;
    }

  const f16* ga  = A + (size_t)(bm + w * 16 + r) * L + q * 8;
  const f16* gb0 = Bt + (size_t)(bn + w * 16 + r) * L + q * 8;
  const f16* gb1 = gb0 + (size_t)64 * L;
  const int am = (w >> 1) * 2;
  const int bnn = (w & 1) * 4;

  auto stage = [&](int t, int bi) {
    f16* bA = As + bi * 2048;
    f16* bB = Bs + bi * 4096;
    const size_t k0 = (size_t)t * 32;
    gl_lds16(ga + k0, bA + w * 512);
    gl_lds16(gb0 + k0, bB + w * 512);
    gl_lds16(gb1 + k0, bB + 2048 + w * 512);
  };
  auto compute = [&](int bi) {
    const f16* bA = As + bi * 2048;
    const f16* bB = Bs + bi * 4096;
    f16x8 af[2], bf[4];
#pragma unroll
    for (int u = 0; u < 2; ++u)
      af[u] = *(const f16x8*)&bA[(am + u) * 512 + q * 128 + r * 8];
#pragma unroll
    for (int u = 0; u < 4; ++u)
      bf[u] = *(const f16x8*)&bB[(bnn + u) * 512 + q * 128 + r * 8];
#pragma unroll
    for (int i = 0; i < 2; ++i)
#pragma unroll
      for (int j = 0; j < 4; ++j)
        acc[i][j] = __builtin_amdgcn_mfma_f32_16x16x32_f16(af[i], bf[j],
                                                           acc[i][j], 0, 0, 0);
  };

  // NT = 18 K-steps of 32. 3 loads per stage -> counted vmcnt(3).
  stage(0, 0);
  stage(1, 1);
  int bi = 0;
  for (int t = 0; t < 16; ++t) {
    asm volatile("s_waitcnt vmcnt(3)" ::: "memory");  // stage(t) landed
    __builtin_amdgcn_s_barrier();
    __builtin_amdgcn_sched_barrier(0);
    stage(t + 2, bi == 0 ? 2 : bi - 1);
    compute(bi);
    bi = (bi == 2) ? 0 : bi + 1;
  }
  asm volatile("s_waitcnt vmcnt(3)" ::: "memory");    // stage(16) landed
  __builtin_amdgcn_s_barrier();
  __builtin_amdgcn_sched_barrier(0);
  compute(bi);
  bi = (bi == 2) ? 0 : bi + 1;
  asm volatile("s_waitcnt vmcnt(0)" ::: "memory");    // stage(17) landed
  __builtin_amdgcn_s_barrier();
  __builtin_amdgcn_sched_barrier(0);
  compute(bi);

  const int cn = bn + wn + r;
#pragma unroll
  for (int i = 0; i < 2; ++i) {
    int rm = bm + wm + i * 16 + q * 4;
#pragma unroll
    for (int j = 0; j < 4; ++j)
#pragma unroll
      for (int rr = 0; rr < 4; ++rr)
        C[(size_t)(rm + rr) * PS + cn + j * 16] = acc[i][j][rr];
  }
}

// ------- row softmax: attnT[p][l] f16 = softmax_l(scoresT[p][l]*scale) ------
__global__ __launch_bounds__(256) void csa_softmax(
    const float* __restrict__ scoresT, const float* __restrict__ scale,
    f16* __restrict__ attnT) {
  const int wv = threadIdx.x >> 6;
  const int lane = threadIdx.x & 63;
  const int p = blockIdx.x * 4 + wv;
  const int n = blockIdx.y;
  const float sc = scale[n];
  const float* row = scoresT + ((size_t)n * PS + p) * L;
  float v[9];
  float m = -1e30f;
#pragma unroll
  for (int j = 0; j < 9; ++j) {
    v[j] = row[lane + j * 64] * sc;
    m = fmaxf(m, v[j]);
  }
#pragma unroll
  for (int off = 32; off > 0; off >>= 1) m = fmaxf(m, __shfl_xor(m, off));
  float e[9], s = 0.f;
#pragma unroll
  for (int j = 0; j < 9; ++j) {
    e[j] = __expf(v[j] - m);
    s += e[j];
  }
#pragma unroll
  for (int off = 32; off > 0; off >>= 1) s += __shfl_xor(s, off);
  const float inv = 1.f / s;
  f16* orow = attnT + ((size_t)n * PS + p) * L;
#pragma unroll
  for (int j = 0; j < 9; ++j) orow[lane + j * 64] = (f16)(e[j] * inv);
}

// ------ fused: res = gather(D)/6 (LDS tile) -> conv3 8x8 -> out -------------
__global__ __launch_bounds__(256) void csa_gather_conv(
    const float* __restrict__ D, const float* __restrict__ wr,
    const float* __restrict__ br, float* __restrict__ out) {
  __shared__ float rs[BAND][18][18];
  __shared__ float wsm[BAND * BAND * 9];
  __shared__ float brs[BAND];
  const int tid = threadIdx.x;
  const int n = blockIdx.z;
  const int ty = blockIdx.y, tx = blockIdx.x;
  const float* Dn = D + (size_t)n * MV * PS;

  for (int i = tid; i < BAND * BAND * 9; i += 256) wsm[i] = wr[i];
  if (tid < BAND) brs[tid] = br[tid];

  for (int idx = tid; idx < BAND * 18 * 18; idx += 256) {
    int ci = idx / 324;
    int rem = idx - ci * 324;
    int yy = rem / 18;
    int xx = rem - yy * 18;
    int oy = ty * 16 - 1 + yy;
    int ox = tx * 16 - 1 + xx;
    float s = 0.f;
    if (oy >= 0 && oy < HO && ox >= 0 && ox < HO) {
      int kh0 = oy & 3;
      int kw0 = ox & 3;
      for (int kh = kh0; kh < 5; kh += 4) {
        int y = (oy - kh) >> 2;
        if (y < 0 || y >= 96) continue;
        for (int kw = kw0; kw < 5; kw += 4) {
          int x = (ox - kw) >> 2;
          if (x < 0 || x >= 96) continue;
          s += Dn[(size_t)(ci * 25 + kh * 5 + kw) * PS + y * 96 + x];
        }
      }
      s *= (1.f / 6.f);
    }
    rs[ci][yy][xx] = s;
  }
  __syncthreads();

  const int y = tid >> 4, x = tid & 15;
  const int oy = ty * 16 + y, ox = tx * 16 + x;
  if (oy >= HO || ox >= HO) return;
  float p[BAND][9];
#pragma unroll
  for (int ci = 0; ci < BAND; ++ci)
#pragma unroll
    for (int dy = 0; dy < 3; ++dy)
#pragma unroll
      for (int dx = 0; dx < 3; ++dx)
        p[ci][dy * 3 + dx] = rs[ci][y + dy][x + dx];
  float* op = out + ((size_t)n * BAND * HO + oy) * HO + ox;
  for (int co = 0; co < BAND; ++co) {
    float acc = brs[co];
#pragma unroll
    for (int ci = 0; ci < BAND; ++ci)
#pragma unroll
      for (int k = 0; k < 9; ++k)
        acc = fmaf(p[ci][k], wsm[(co * BAND + ci) * 9 + k], acc);
    acc = acc > 0.f ? acc : 0.01f * acc;
    op[(size_t)co * HO * HO] = acc;
  }
}

// ---------------------------------------------------------------------------
extern "C" void kernel_launch(void* const* d_in, const int* in_sizes, int n_in,
                              void* d_out, int out_size, void* d_ws,
                              size_t ws_size, hipStream_t stream) {
  const float* ms   = (const float*)d_in[0];
  const float* pan  = (const float*)d_in[1];
  const float* pan2 = (const float*)d_in[2];
  const float* wq = (const float*)d_in[3];
  const float* bq = (const float*)d_in[4];
  const float* wk = (const float*)d_in[5];
  const float* bk = (const float*)d_in[6];
  const float* wv = (const float*)d_in[7];
  const float* bv = (const float*)d_in[8];
  const float* wr = (const float*)d_in[9];
  const float* br = (const float*)d_in[10];
  float* out = (float*)d_out;

  char* ws = (char*)d_ws;
  f16*   qps   = (f16*)(ws + OFF_QPS);
  f16*   kcl   = (f16*)(ws + OFF_KCL);
  float* v_fea = (float*)(ws + OFF_VFEA);
  float* n2    = (float*)(ws + OFF_N2);
  float* scale = (float*)(ws + OFF_SC);
  f16*   Kmat  = (f16*)(ws + OFF_KM);
  f16*   Vt    = (f16*)(ws + OFF_VT);
  float* scoT  = (float*)(ws + OFF_ST);
  f16*   attnT = (f16*)(ws + OFF_AT);
  float* Dm    = (float*)(ws + OFF_D);

  dim3 b256(256);
  csa_convs<<<dim3(NBQ + 2 * NBC), b256, 0, stream>>>(
      pan, wq, bq, qps, pan2, wk, bk, kcl, ms, wv, bv, v_fea);
  csa_build_patches<<<dim3(NB * LP), b256, 0, stream>>>(kcl, v_fea, Kmat, Vt,
                                                        n2);
  csa_max_scale<<<dim3(NB), b256, 0, stream>>>(n2, scale);

  // GEMM1: scoresT[PS][L] = implicit-Q x Kmat^T
  csa_gemm1<<<dim3(LP / 128, PS / 128, NB), b256, 0, stream>>>(qps, Kmat,
                                                               scoT);

  csa_softmax<<<dim3(PS / 4, NB), b256, 0, stream>>>(scoT, scale, attnT);

  // GEMM2: D[MV][PS] = Vt[MV][L] x attnT[PS][L]^T (64x128 tiles)
  csa_gemm2<<<dim3(PS / 128, MV / 64, NB), b256, 0, stream>>>(Vt, attnT, Dm);

  // fused gather + final conv3 8x8 -> out
  csa_gather_conv<<<dim3((HO + 15) / 16, (HO + 15) / 16, NB), b256, 0,
                    stream>>>(Dm, wr, br, out);
}